// Round 5
// baseline (264.434 us; speedup 1.0000x reference)
//
#include <hip/hip_runtime.h>
#include <hip/hip_bf16.h>
#include <math.h>

#define N_NODESC 100000
#define N_EDGESC 1600000
#define IN_DIMC 256
#define HIDC 64
#define ALPHAC 0.1f
#define BIASC 1e-4f
#define EOSC 1e-10f

#define MC (N_EDGESC + N_NODESC)   // 1,700,000
#define NBUCK 400                  // buckets of 256 nodes (shift 8), per side
#define NBUCK_USED 391             // ceil(N_NODES / 256)
#define BSHIFT 8
#define BMASK 255
#define BCAP 5120u                 // expected ~4000/bucket, +17 sigma
#define W20SCALE 1048576.0f        // 2^20
#define W20INV (1.0f / 1048576.0f)
#define SUMMASK ((1ull << 40) - 1)
#define CNTONE (1ull << 40)
#define EPB 8                      // edges per thread in edge_scatter

typedef __attribute__((ext_vector_type(8))) short short8;
typedef __attribute__((ext_vector_type(4))) float f32x4;

#define WT_STRIDE 264  // bf16 per j-row: 256 + 8 pad (528 B, 16B-aligned)

// edges may arrive as int32 (JAX x64-off) or int64 little-endian.
__device__ inline void load_edge(const int* __restrict__ edges, int e, int is64,
                                 int& src, int& dst) {
    if (is64) {
        const int2 a = ((const int2*)edges)[e];
        const int2 b = ((const int2*)edges)[N_EDGESC + e];
        src = a.x; dst = b.x;
    } else {
        src = edges[e];
        dst = edges[N_EDGESC + e];
    }
}

__device__ inline short pkbf(float x) {
    union { __hip_bfloat16 b; short s; } u;
    u.b = __float2bfloat16(x);
    return u.s;
}

// ---------------------------------------------------------------------------
// node kernel (MFMA): q[n] = relu(feat[n] @ W + b) @ (We[:64]+We[64:])
// 2 node-tiles per wave. Block 0 zeroes the packed u64 cursors + detects
// int32/int64 edge layout.
__global__ __launch_bounds__(256, 3) void node_kernel(
    const float* __restrict__ features,
    const float* __restrict__ W_emb,
    const float* __restrict__ b_emb,
    const float* __restrict__ W_edge,
    const int* __restrict__ edges,
    float* __restrict__ q,
    unsigned long long* __restrict__ cursor64,
    int* __restrict__ flag) {
    __shared__ __align__(16) short Wt[HIDC * WT_STRIDE];  // ~33.8 KB
    const int tid = threadIdx.x;
    if (blockIdx.x == 0) {
        if (tid == 0) {
            int z = 0;
            #pragma unroll
            for (int i = 0; i < 16; ++i) z |= edges[2 * i + 1];
            *flag = (z == 0) ? 1 : 0;  // 1 => int64 layout
        }
        for (int b = tid; b < NBUCK; b += 256) cursor64[b] = 0ull;
    }
    {
        const float4* Wg = (const float4*)W_emb;
        #pragma unroll
        for (int i = 0; i < 16; ++i) {
            const int f4 = tid + 256 * i;
            const float4 g = Wg[f4];
            const int flat = 4 * f4;
            const int k = flat >> 6;
            const int j0 = flat & 63;
            Wt[(j0 + 0) * WT_STRIDE + k] = pkbf(g.x);
            Wt[(j0 + 1) * WT_STRIDE + k] = pkbf(g.y);
            Wt[(j0 + 2) * WT_STRIDE + k] = pkbf(g.z);
            Wt[(j0 + 3) * WT_STRIDE + k] = pkbf(g.w);
        }
    }
    const int lane = tid & 63;
    const int wave = tid >> 6;
    const int quad = lane >> 4;
    const int m = lane & 15;
    f32x4 accA[4], accB[4];
    float wsum4[4];
    #pragma unroll
    for (int nt = 0; nt < 4; ++nt) {
        const int j = m + 16 * nt;
        const float b = b_emb[j];
        accA[nt] = (f32x4){b, b, b, b};
        accB[nt] = (f32x4){b, b, b, b};
        wsum4[nt] = W_edge[j] + W_edge[HIDC + j];
    }
    __syncthreads();

    const int node0A = blockIdx.x * 128 + wave * 16;
    const int node0B = node0A + 64;
    const float* frA = features + (size_t)min(node0A + m, N_NODESC - 1) * IN_DIMC;
    const float* frB = features + (size_t)min(node0B + m, N_NODESC - 1) * IN_DIMC;

    #pragma unroll
    for (int ks = 0; ks < 8; ++ks) {
        const int kk = ks * 32 + quad * 8;
        const float4 fa0 = *(const float4*)(frA + kk);
        const float4 fb0 = *(const float4*)(frA + kk + 4);
        const float4 fa1 = *(const float4*)(frB + kk);
        const float4 fb1 = *(const float4*)(frB + kk + 4);
        short8 afA, afB;
        afA[0] = pkbf(fa0.x); afA[1] = pkbf(fa0.y);
        afA[2] = pkbf(fa0.z); afA[3] = pkbf(fa0.w);
        afA[4] = pkbf(fb0.x); afA[5] = pkbf(fb0.y);
        afA[6] = pkbf(fb0.z); afA[7] = pkbf(fb0.w);
        afB[0] = pkbf(fa1.x); afB[1] = pkbf(fa1.y);
        afB[2] = pkbf(fa1.z); afB[3] = pkbf(fa1.w);
        afB[4] = pkbf(fb1.x); afB[5] = pkbf(fb1.y);
        afB[6] = pkbf(fb1.z); afB[7] = pkbf(fb1.w);
        #pragma unroll
        for (int nt = 0; nt < 4; ++nt) {
            const short8 bf =
                *(const short8*)&Wt[(m + 16 * nt) * WT_STRIDE + kk];
            accA[nt] = __builtin_amdgcn_mfma_f32_16x16x32_bf16(afA, bf, accA[nt],
                                                               0, 0, 0);
            accB[nt] = __builtin_amdgcn_mfma_f32_16x16x32_bf16(afB, bf, accB[nt],
                                                               0, 0, 0);
        }
    }

    #pragma unroll
    for (int r = 0; r < 4; ++r) {
        float sA = 0.f, sB = 0.f;
        #pragma unroll
        for (int nt = 0; nt < 4; ++nt) {
            sA = fmaf(fmaxf(accA[nt][r], 0.f), wsum4[nt], sA);
            sB = fmaf(fmaxf(accB[nt][r], 0.f), wsum4[nt], sB);
        }
        sA += __shfl_xor(sA, 1); sA += __shfl_xor(sA, 2);
        sA += __shfl_xor(sA, 4); sA += __shfl_xor(sA, 8);
        sB += __shfl_xor(sB, 1); sB += __shfl_xor(sB, 2);
        sB += __shfl_xor(sB, 4); sB += __shfl_xor(sB, 8);
        if (m == 0) {
            const int nA = node0A + quad * 4 + r;
            const int nB = node0B + quad * 4 + r;
            if (nA < N_NODESC) q[nA] = sA;
            if (nB < N_NODESC) q[nB] = sB;
        }
    }
}

// ---------------------------------------------------------------------------
// edge_scatter: 8 edges/thread, batched phases:
// all edge loads -> all q gathers -> compute+rank -> claim (ONE u64 atomic per
// bucket covers both sides) -> scatter.
// Records: u32 = (node_local_8b << 20) | wlp_fixed_20b, into ws bucket arrays.
__global__ __launch_bounds__(256) void edge_scatter(
    const int* __restrict__ edges,
    const float* __restrict__ noise,
    const float* __restrict__ b_edge,
    const float* __restrict__ q,
    unsigned long long* __restrict__ cursor64,
    unsigned* __restrict__ recS,
    unsigned* __restrict__ recD,
    float* __restrict__ out,
    const int* __restrict__ flag) {
    __shared__ unsigned hist[2][4][NBUCK];   // 12.8 KB
    __shared__ unsigned wbase[2][4][NBUCK];  // 12.8 KB
    const int tid = threadIdx.x;
    const int wave = tid >> 6;
    for (int i = tid; i < 2 * 4 * NBUCK; i += 256)
        ((unsigned*)hist)[i] = 0u;
    __syncthreads();
    const int is64 = *flag;
    const float be = b_edge[0];
    const int e0 = blockIdx.x * (256 * EPB) + tid;

    int sA[EPB], dA[EPB];
    #pragma unroll
    for (int i = 0; i < EPB; ++i) {
        const int e = e0 + i * 256;
        sA[i] = -1;
        if (e < N_EDGESC) load_edge(edges, e, is64, sA[i], dA[i]);
    }
    float qs[EPB], qd[EPB];
    #pragma unroll
    for (int i = 0; i < EPB; ++i) {
        if (sA[i] >= 0) { qs[i] = q[sA[i]]; qd[i] = q[dA[i]]; }
    }
    float wlpA[EPB];
    unsigned rkS[EPB], rkD[EPB];
    #pragma unroll
    for (int i = 0; i < EPB; ++i) {
        if (sA[i] >= 0) {
            const int e = e0 + i * 256;
            const float raw = 0.5f * (qs[i] + qd[i]) + be;
            const float u = noise[e];
            const float eps = (BIASC - (1.0f - BIASC)) * u + (1.0f - BIASC);
            const float gate = logf(eps) - log1pf(-eps);
            const float wlp = 1.0f / (1.0f + expf(-(gate + raw)));
            wlpA[i] = wlp;
            out[2 * MC + e] = wlp;
            out[2 * MC + N_EDGESC + e] = 1.0f - wlp;
            rkS[i] = atomicAdd(&hist[0][wave][sA[i] >> BSHIFT], 1u);
            rkD[i] = atomicAdd(&hist[1][wave][dA[i] >> BSHIFT], 1u);
        }
    }
    __syncthreads();
    // claim phase: one u64 atomic claims S (low 32) and D (high 32) cursors.
    for (int b = tid; b < NBUCK; b += 256) {
        const unsigned s0 = hist[0][0][b], s1 = hist[0][1][b];
        const unsigned s2 = hist[0][2][b], s3 = hist[0][3][b];
        const unsigned d0 = hist[1][0][b], d1 = hist[1][1][b];
        const unsigned d2 = hist[1][2][b], d3 = hist[1][3][b];
        const unsigned long long add =
            (unsigned long long)(s0 + s1 + s2 + s3) |
            ((unsigned long long)(d0 + d1 + d2 + d3) << 32);
        const unsigned long long old = atomicAdd(&cursor64[b], add);
        const unsigned baseS = (unsigned)old;
        const unsigned baseD = (unsigned)(old >> 32);
        wbase[0][0][b] = baseS;
        wbase[0][1][b] = baseS + s0;
        wbase[0][2][b] = baseS + s0 + s1;
        wbase[0][3][b] = baseS + s0 + s1 + s2;
        wbase[1][0][b] = baseD;
        wbase[1][1][b] = baseD + d0;
        wbase[1][2][b] = baseD + d0 + d1;
        wbase[1][3][b] = baseD + d0 + d1 + d2;
    }
    __syncthreads();
    #pragma unroll
    for (int i = 0; i < EPB; ++i) {
        if (sA[i] >= 0) {
            const int s = sA[i], d = dA[i];
            const unsigned w20 =
                min((unsigned)(wlpA[i] * W20SCALE + 0.5f), 0xFFFFFu);
            const unsigned pS = wbase[0][wave][s >> BSHIFT] + rkS[i];
            const unsigned pD = wbase[1][wave][d >> BSHIFT] + rkD[i];
            if (pS < BCAP)
                recS[(unsigned)(s >> BSHIFT) * BCAP + pS] =
                    ((unsigned)(s & BMASK) << 20) | w20;
            if (pD < BCAP)
                recD[(unsigned)(d >> BSHIFT) * BCAP + pD] =
                    ((unsigned)(d & BMASK) << 20) | w20;
        }
    }
}

// ---------------------------------------------------------------------------
// gather_kernel: block owns one bucket, BOTH sides (S table in [0,256),
// D table in [256,512)). Decode -> rS/rD float2 rsqrt pairs + the two
// self-loop outputs for its nodes.
__global__ __launch_bounds__(256) void gather_kernel(
    const unsigned* __restrict__ recS,
    const unsigned* __restrict__ recD,
    const unsigned long long* __restrict__ cursor64,
    float2* __restrict__ rS,
    float2* __restrict__ rD,
    float* __restrict__ out) {
    __shared__ unsigned long long table[512];
    const int bkt = blockIdx.x;
    const unsigned long long c = cursor64[bkt];
    const unsigned cntS = min((unsigned)c, BCAP);
    const unsigned cntD = min((unsigned)(c >> 32), BCAP);
    const unsigned* rs = recS + (unsigned)bkt * BCAP;
    const unsigned* rd = recD + (unsigned)bkt * BCAP;
    const int tid = threadIdx.x;
    table[tid] = 0ull;
    table[tid + 256] = 0ull;
    __syncthreads();
    for (unsigned i = tid; i < cntS; i += 256) {
        const unsigned r = rs[i];
        atomicAdd(&table[r >> 20], CNTONE | (unsigned long long)(r & 0xFFFFFu));
    }
    for (unsigned i = tid; i < cntD; i += 256) {
        const unsigned r = rd[i];
        atomicAdd(&table[256 + (r >> 20)],
                  CNTONE | (unsigned long long)(r & 0xFFFFFu));
    }
    __syncthreads();
    const int node = (bkt << BSHIFT) + tid;
    if (node < N_NODESC) {
        const unsigned long long aS = table[tid];
        const unsigned long long aD = table[tid + 256];
        const float sumS = (float)(aS & SUMMASK) * W20INV;
        const float cS = (float)(aS >> 40);
        const float sumD = (float)(aD & SUMMASK) * W20INV;
        const float cD = (float)(aD >> 40);
        float2 vS, vD;
        vS.x = rsqrtf(1.0f + sumS);        // lp out-degree (self-loop = 1)
        vS.y = rsqrtf(1.0f + cS - sumS);   // hp out-degree
        vD.x = rsqrtf(1.0f + sumD);        // lp in-degree
        vD.y = rsqrtf(1.0f + cD - sumD);   // hp in-degree
        rS[node] = vS;
        rD[node] = vD;
        // self-loop outputs (edge index N_EDGESC + node)
        out[N_EDGESC + node] = (1.0f + EOSC) * vS.x * vD.x;
        out[MC + N_EDGESC + node] = 1.0f;
    }
}

// ---------------------------------------------------------------------------
// final kernel: pure edges, 4 per thread. Reads only wlp (wh = 1-wlp
// recomputed, bit-identical), gathers rS/rD, writes both normalized outputs.
__global__ __launch_bounds__(256) void final_kernel(
    const int* __restrict__ edges,
    const float2* __restrict__ rS,
    const float2* __restrict__ rD,
    float* __restrict__ out,
    const int* __restrict__ flag) {
    const int tid = threadIdx.x;
    const int i0 = blockIdx.x * 1024 + tid;
    const int is64 = *flag;
    int sA[4], dA[4];
    float wl[4], wh[4];
    #pragma unroll
    for (int j = 0; j < 4; ++j) {
        const int i = i0 + j * 256;
        sA[j] = -1;
        if (i < N_EDGESC) load_edge(edges, i, is64, sA[j], dA[j]);
    }
    #pragma unroll
    for (int j = 0; j < 4; ++j) {
        const int i = i0 + j * 256;
        if (sA[j] >= 0) {
            const float wlp = out[2 * MC + i];
            wl[j] = wlp + EOSC;
            wh[j] = (1.0f - wlp) + EOSC;
        }
    }
    float2 a[4], b[4];
    #pragma unroll
    for (int j = 0; j < 4; ++j) {
        if (sA[j] >= 0) { a[j] = rS[sA[j]]; b[j] = rD[dA[j]]; }
    }
    #pragma unroll
    for (int j = 0; j < 4; ++j) {
        const int i = i0 + j * 256;
        if (sA[j] >= 0) {
            out[i] = wl[j] * a[j].x * b[j].x;
            out[MC + i] = -ALPHAC * wh[j] * a[j].y * b[j].y;
        }
    }
}

// ---------------------------------------------------------------------------
extern "C" void kernel_launch(void* const* d_in, const int* in_sizes, int n_in,
                              void* d_out, int out_size, void* d_ws, size_t ws_size,
                              hipStream_t stream) {
    const float* features = (const float*)d_in[0];
    const int* edges      = (const int*)d_in[1];
    const float* noise    = (const float*)d_in[2];
    const float* W_emb    = (const float*)d_in[3];
    const float* b_emb    = (const float*)d_in[4];
    const float* W_edge   = (const float*)d_in[5];
    const float* b_edge   = (const float*)d_in[6];
    float* out = (float*)d_out;
    char* ws = (char*)d_ws;

    // ws layout (bytes):
    //   [0, 400000)            q  : N f32
    //   [400000, 1200000)      rS : N float2
    //   [1200000, 2000000)     rD : N float2
    //   [2000000, 2000004)     flag
    //   [2000064, 2003264)     cursor64 : 400 u64 (S low 32 | D high 32)
    //   [2097152, 10289152)    recS : 400*5120 u32
    //   [10289152, 18481152)   recD : 400*5120 u32
    float* q = (float*)ws;
    float2* rS = (float2*)(ws + 400000);
    float2* rD = (float2*)(ws + 1200000);
    int* flag = (int*)(ws + 2000000);
    unsigned long long* cursor64 = (unsigned long long*)(ws + 2000064);
    unsigned* recS = (unsigned*)(ws + 2097152);
    unsigned* recD = (unsigned*)(ws + 10289152);

    node_kernel<<<782, 256, 0, stream>>>(features, W_emb, b_emb, W_edge, edges,
                                         q, cursor64, flag);
    edge_scatter<<<(N_EDGESC + 256 * EPB - 1) / (256 * EPB), 256, 0, stream>>>(
        edges, noise, b_edge, q, cursor64, recS, recD, out, flag);
    gather_kernel<<<NBUCK_USED, 256, 0, stream>>>(recS, recD, cursor64, rS, rD,
                                                  out);
    final_kernel<<<(N_EDGESC + 1023) / 1024, 256, 0, stream>>>(edges, rS, rD,
                                                               out, flag);
}

// Round 6
// 263.097 us; speedup vs baseline: 1.0051x; 1.0051x over previous
//
#include <hip/hip_runtime.h>
#include <hip/hip_bf16.h>
#include <math.h>

#define N_NODESC 100000
#define N_EDGESC 1600000
#define IN_DIMC 256
#define HIDC 64
#define ALPHAC 0.1f
#define BIASC 1e-4f
#define EOSC 1e-10f

#define MC (N_EDGESC + N_NODESC)   // 1,700,000
#define NBUCK 400                  // buckets of 256 nodes (shift 8), per side
#define NBUCK_USED 391             // ceil(N_NODES / 256)
#define BSHIFT 8
#define BMASK 255
#define BCAP 5120u                 // expected ~4000/bucket, +17 sigma
#define W20SCALE 1048576.0f        // 2^20
#define W20INV (1.0f / 1048576.0f)
#define SUMMASK ((1ull << 40) - 1)
#define CNTONE (1ull << 40)
#define EPB 4                      // edges per thread in edge_scatter (512 thr)
#define NWAVE 8                    // waves per edge_scatter block

typedef __attribute__((ext_vector_type(8))) short short8;
typedef __attribute__((ext_vector_type(4))) float f32x4;

#define WT_STRIDE 264  // bf16 per j-row: 256 + 8 pad (528 B, 16B-aligned)

// edges may arrive as int32 (JAX x64-off) or int64 little-endian.
__device__ inline void load_edge(const int* __restrict__ edges, int e, int is64,
                                 int& src, int& dst) {
    if (is64) {
        const int2 a = ((const int2*)edges)[e];
        const int2 b = ((const int2*)edges)[N_EDGESC + e];
        src = a.x; dst = b.x;
    } else {
        src = edges[e];
        dst = edges[N_EDGESC + e];
    }
}

__device__ inline short pkbf(float x) {
    union { __hip_bfloat16 b; short s; } u;
    u.b = __float2bfloat16(x);
    return u.s;
}

// ---------------------------------------------------------------------------
// node kernel (MFMA): q[n] = relu(feat[n] @ W + b) @ (We[:64]+We[64:])
// 2 node-tiles per wave. Block 0 zeroes the packed u64 cursors + detects
// int32/int64 edge layout.
__global__ __launch_bounds__(256, 3) void node_kernel(
    const float* __restrict__ features,
    const float* __restrict__ W_emb,
    const float* __restrict__ b_emb,
    const float* __restrict__ W_edge,
    const int* __restrict__ edges,
    float* __restrict__ q,
    unsigned long long* __restrict__ cursor64,
    int* __restrict__ flag) {
    __shared__ __align__(16) short Wt[HIDC * WT_STRIDE];  // ~33.8 KB
    const int tid = threadIdx.x;
    if (blockIdx.x == 0) {
        if (tid == 0) {
            int z = 0;
            #pragma unroll
            for (int i = 0; i < 16; ++i) z |= edges[2 * i + 1];
            *flag = (z == 0) ? 1 : 0;  // 1 => int64 layout
        }
        for (int b = tid; b < NBUCK; b += 256) cursor64[b] = 0ull;
    }
    {
        const float4* Wg = (const float4*)W_emb;
        #pragma unroll
        for (int i = 0; i < 16; ++i) {
            const int f4 = tid + 256 * i;
            const float4 g = Wg[f4];
            const int flat = 4 * f4;
            const int k = flat >> 6;
            const int j0 = flat & 63;
            Wt[(j0 + 0) * WT_STRIDE + k] = pkbf(g.x);
            Wt[(j0 + 1) * WT_STRIDE + k] = pkbf(g.y);
            Wt[(j0 + 2) * WT_STRIDE + k] = pkbf(g.z);
            Wt[(j0 + 3) * WT_STRIDE + k] = pkbf(g.w);
        }
    }
    const int lane = tid & 63;
    const int wave = tid >> 6;
    const int quad = lane >> 4;
    const int m = lane & 15;
    f32x4 accA[4], accB[4];
    float wsum4[4];
    #pragma unroll
    for (int nt = 0; nt < 4; ++nt) {
        const int j = m + 16 * nt;
        const float b = b_emb[j];
        accA[nt] = (f32x4){b, b, b, b};
        accB[nt] = (f32x4){b, b, b, b};
        wsum4[nt] = W_edge[j] + W_edge[HIDC + j];
    }
    __syncthreads();

    const int node0A = blockIdx.x * 128 + wave * 16;
    const int node0B = node0A + 64;
    const float* frA = features + (size_t)min(node0A + m, N_NODESC - 1) * IN_DIMC;
    const float* frB = features + (size_t)min(node0B + m, N_NODESC - 1) * IN_DIMC;

    #pragma unroll
    for (int ks = 0; ks < 8; ++ks) {
        const int kk = ks * 32 + quad * 8;
        const float4 fa0 = *(const float4*)(frA + kk);
        const float4 fb0 = *(const float4*)(frA + kk + 4);
        const float4 fa1 = *(const float4*)(frB + kk);
        const float4 fb1 = *(const float4*)(frB + kk + 4);
        short8 afA, afB;
        afA[0] = pkbf(fa0.x); afA[1] = pkbf(fa0.y);
        afA[2] = pkbf(fa0.z); afA[3] = pkbf(fa0.w);
        afA[4] = pkbf(fb0.x); afA[5] = pkbf(fb0.y);
        afA[6] = pkbf(fb0.z); afA[7] = pkbf(fb0.w);
        afB[0] = pkbf(fa1.x); afB[1] = pkbf(fa1.y);
        afB[2] = pkbf(fa1.z); afB[3] = pkbf(fa1.w);
        afB[4] = pkbf(fb1.x); afB[5] = pkbf(fb1.y);
        afB[6] = pkbf(fb1.z); afB[7] = pkbf(fb1.w);
        #pragma unroll
        for (int nt = 0; nt < 4; ++nt) {
            const short8 bf =
                *(const short8*)&Wt[(m + 16 * nt) * WT_STRIDE + kk];
            accA[nt] = __builtin_amdgcn_mfma_f32_16x16x32_bf16(afA, bf, accA[nt],
                                                               0, 0, 0);
            accB[nt] = __builtin_amdgcn_mfma_f32_16x16x32_bf16(afB, bf, accB[nt],
                                                               0, 0, 0);
        }
    }

    #pragma unroll
    for (int r = 0; r < 4; ++r) {
        float sA = 0.f, sB = 0.f;
        #pragma unroll
        for (int nt = 0; nt < 4; ++nt) {
            sA = fmaf(fmaxf(accA[nt][r], 0.f), wsum4[nt], sA);
            sB = fmaf(fmaxf(accB[nt][r], 0.f), wsum4[nt], sB);
        }
        sA += __shfl_xor(sA, 1); sA += __shfl_xor(sA, 2);
        sA += __shfl_xor(sA, 4); sA += __shfl_xor(sA, 8);
        sB += __shfl_xor(sB, 1); sB += __shfl_xor(sB, 2);
        sB += __shfl_xor(sB, 4); sB += __shfl_xor(sB, 8);
        if (m == 0) {
            const int nA = node0A + quad * 4 + r;
            const int nB = node0B + quad * 4 + r;
            if (nA < N_NODESC) q[nA] = sA;
            if (nB < N_NODESC) q[nB] = sB;
        }
    }
}

// ---------------------------------------------------------------------------
// edge_scatter: 512 threads (8 waves), 4 edges/thread => 2048 edges/block,
// 782 blocks (3/CU, 24 waves/CU). Batched phases:
// all edge loads -> all q gathers -> compute+rank -> claim (ONE u64 atomic per
// bucket covers both sides, single pass) -> scatter.
// Records: u32 = (node_local_8b << 20) | wlp_fixed_20b, into ws bucket arrays.
__global__ __launch_bounds__(512) void edge_scatter(
    const int* __restrict__ edges,
    const float* __restrict__ noise,
    const float* __restrict__ b_edge,
    const float* __restrict__ q,
    unsigned long long* __restrict__ cursor64,
    unsigned* __restrict__ recS,
    unsigned* __restrict__ recD,
    float* __restrict__ out,
    const int* __restrict__ flag) {
    __shared__ unsigned hist[2][NWAVE][NBUCK];   // 25.6 KB
    __shared__ unsigned wbase[2][NWAVE][NBUCK];  // 25.6 KB
    const int tid = threadIdx.x;
    const int wave = tid >> 6;
    for (int i = tid; i < 2 * NWAVE * NBUCK; i += 512)
        ((unsigned*)hist)[i] = 0u;
    __syncthreads();
    const int is64 = *flag;
    const float be = b_edge[0];
    const int e0 = blockIdx.x * (512 * EPB) + tid;

    int sA[EPB], dA[EPB];
    #pragma unroll
    for (int i = 0; i < EPB; ++i) {
        const int e = e0 + i * 512;
        sA[i] = -1;
        if (e < N_EDGESC) load_edge(edges, e, is64, sA[i], dA[i]);
    }
    float qs[EPB], qd[EPB];
    #pragma unroll
    for (int i = 0; i < EPB; ++i) {
        if (sA[i] >= 0) { qs[i] = q[sA[i]]; qd[i] = q[dA[i]]; }
    }
    float wlpA[EPB];
    unsigned rkS[EPB], rkD[EPB];
    #pragma unroll
    for (int i = 0; i < EPB; ++i) {
        if (sA[i] >= 0) {
            const int e = e0 + i * 512;
            const float raw = 0.5f * (qs[i] + qd[i]) + be;
            const float u = noise[e];
            const float eps = (BIASC - (1.0f - BIASC)) * u + (1.0f - BIASC);
            const float gate = logf(eps) - log1pf(-eps);
            const float wlp = 1.0f / (1.0f + expf(-(gate + raw)));
            wlpA[i] = wlp;
            out[2 * MC + e] = wlp;
            out[2 * MC + N_EDGESC + e] = 1.0f - wlp;
            rkS[i] = atomicAdd(&hist[0][wave][sA[i] >> BSHIFT], 1u);
            rkD[i] = atomicAdd(&hist[1][wave][dA[i] >> BSHIFT], 1u);
        }
    }
    __syncthreads();
    // claim phase: single pass; one u64 atomic claims S (low 32) and D (high
    // 32) cursors for bucket tid.
    if (tid < NBUCK) {
        const int b = tid;
        unsigned ps[NWAVE], pd[NWAVE];
        unsigned totS = 0, totD = 0;
        #pragma unroll
        for (int w = 0; w < NWAVE; ++w) {
            ps[w] = totS; totS += hist[0][w][b];
            pd[w] = totD; totD += hist[1][w][b];
        }
        const unsigned long long add =
            (unsigned long long)totS | ((unsigned long long)totD << 32);
        const unsigned long long old = atomicAdd(&cursor64[b], add);
        const unsigned baseS = (unsigned)old;
        const unsigned baseD = (unsigned)(old >> 32);
        #pragma unroll
        for (int w = 0; w < NWAVE; ++w) {
            wbase[0][w][b] = baseS + ps[w];
            wbase[1][w][b] = baseD + pd[w];
        }
    }
    __syncthreads();
    #pragma unroll
    for (int i = 0; i < EPB; ++i) {
        if (sA[i] >= 0) {
            const int s = sA[i], d = dA[i];
            const unsigned w20 =
                min((unsigned)(wlpA[i] * W20SCALE + 0.5f), 0xFFFFFu);
            const unsigned pS = wbase[0][wave][s >> BSHIFT] + rkS[i];
            const unsigned pD = wbase[1][wave][d >> BSHIFT] + rkD[i];
            if (pS < BCAP)
                recS[(unsigned)(s >> BSHIFT) * BCAP + pS] =
                    ((unsigned)(s & BMASK) << 20) | w20;
            if (pD < BCAP)
                recD[(unsigned)(d >> BSHIFT) * BCAP + pD] =
                    ((unsigned)(d & BMASK) << 20) | w20;
        }
    }
}

// ---------------------------------------------------------------------------
// gather_kernel: block owns one bucket, BOTH sides (S table in [0,256),
// D table in [256,512)). Decode -> rS/rD float2 rsqrt pairs + the two
// self-loop outputs for its nodes.
__global__ __launch_bounds__(256) void gather_kernel(
    const unsigned* __restrict__ recS,
    const unsigned* __restrict__ recD,
    const unsigned long long* __restrict__ cursor64,
    float2* __restrict__ rS,
    float2* __restrict__ rD,
    float* __restrict__ out) {
    __shared__ unsigned long long table[512];
    const int bkt = blockIdx.x;
    const unsigned long long c = cursor64[bkt];
    const unsigned cntS = min((unsigned)c, BCAP);
    const unsigned cntD = min((unsigned)(c >> 32), BCAP);
    const unsigned* rs = recS + (unsigned)bkt * BCAP;
    const unsigned* rd = recD + (unsigned)bkt * BCAP;
    const int tid = threadIdx.x;
    table[tid] = 0ull;
    table[tid + 256] = 0ull;
    __syncthreads();
    for (unsigned i = tid; i < cntS; i += 256) {
        const unsigned r = rs[i];
        atomicAdd(&table[r >> 20], CNTONE | (unsigned long long)(r & 0xFFFFFu));
    }
    for (unsigned i = tid; i < cntD; i += 256) {
        const unsigned r = rd[i];
        atomicAdd(&table[256 + (r >> 20)],
                  CNTONE | (unsigned long long)(r & 0xFFFFFu));
    }
    __syncthreads();
    const int node = (bkt << BSHIFT) + tid;
    if (node < N_NODESC) {
        const unsigned long long aS = table[tid];
        const unsigned long long aD = table[tid + 256];
        const float sumS = (float)(aS & SUMMASK) * W20INV;
        const float cS = (float)(aS >> 40);
        const float sumD = (float)(aD & SUMMASK) * W20INV;
        const float cD = (float)(aD >> 40);
        float2 vS, vD;
        vS.x = rsqrtf(1.0f + sumS);        // lp out-degree (self-loop = 1)
        vS.y = rsqrtf(1.0f + cS - sumS);   // hp out-degree
        vD.x = rsqrtf(1.0f + sumD);        // lp in-degree
        vD.y = rsqrtf(1.0f + cD - sumD);   // hp in-degree
        rS[node] = vS;
        rD[node] = vD;
        // self-loop outputs (edge index N_EDGESC + node)
        out[N_EDGESC + node] = (1.0f + EOSC) * vS.x * vD.x;
        out[MC + N_EDGESC + node] = 1.0f;
    }
}

// ---------------------------------------------------------------------------
// final kernel: pure edges, 4 per thread. Reads only wlp (wh = 1-wlp
// recomputed, bit-identical), gathers rS/rD, writes both normalized outputs.
__global__ __launch_bounds__(256) void final_kernel(
    const int* __restrict__ edges,
    const float2* __restrict__ rS,
    const float2* __restrict__ rD,
    float* __restrict__ out,
    const int* __restrict__ flag) {
    const int tid = threadIdx.x;
    const int i0 = blockIdx.x * 1024 + tid;
    const int is64 = *flag;
    int sA[4], dA[4];
    float wl[4], wh[4];
    #pragma unroll
    for (int j = 0; j < 4; ++j) {
        const int i = i0 + j * 256;
        sA[j] = -1;
        if (i < N_EDGESC) load_edge(edges, i, is64, sA[j], dA[j]);
    }
    #pragma unroll
    for (int j = 0; j < 4; ++j) {
        const int i = i0 + j * 256;
        if (sA[j] >= 0) {
            const float wlp = out[2 * MC + i];
            wl[j] = wlp + EOSC;
            wh[j] = (1.0f - wlp) + EOSC;
        }
    }
    float2 a[4], b[4];
    #pragma unroll
    for (int j = 0; j < 4; ++j) {
        if (sA[j] >= 0) { a[j] = rS[sA[j]]; b[j] = rD[dA[j]]; }
    }
    #pragma unroll
    for (int j = 0; j < 4; ++j) {
        const int i = i0 + j * 256;
        if (sA[j] >= 0) {
            out[i] = wl[j] * a[j].x * b[j].x;
            out[MC + i] = -ALPHAC * wh[j] * a[j].y * b[j].y;
        }
    }
}

// ---------------------------------------------------------------------------
extern "C" void kernel_launch(void* const* d_in, const int* in_sizes, int n_in,
                              void* d_out, int out_size, void* d_ws, size_t ws_size,
                              hipStream_t stream) {
    const float* features = (const float*)d_in[0];
    const int* edges      = (const int*)d_in[1];
    const float* noise    = (const float*)d_in[2];
    const float* W_emb    = (const float*)d_in[3];
    const float* b_emb    = (const float*)d_in[4];
    const float* W_edge   = (const float*)d_in[5];
    const float* b_edge   = (const float*)d_in[6];
    float* out = (float*)d_out;
    char* ws = (char*)d_ws;

    // ws layout (bytes):
    //   [0, 400000)            q  : N f32
    //   [400000, 1200000)      rS : N float2
    //   [1200000, 2000000)     rD : N float2
    //   [2000000, 2000004)     flag
    //   [2000064, 2003264)     cursor64 : 400 u64 (S low 32 | D high 32)
    //   [2097152, 10289152)    recS : 400*5120 u32
    //   [10289152, 18481152)   recD : 400*5120 u32
    float* q = (float*)ws;
    float2* rS = (float2*)(ws + 400000);
    float2* rD = (float2*)(ws + 1200000);
    int* flag = (int*)(ws + 2000000);
    unsigned long long* cursor64 = (unsigned long long*)(ws + 2000064);
    unsigned* recS = (unsigned*)(ws + 2097152);
    unsigned* recD = (unsigned*)(ws + 10289152);

    node_kernel<<<782, 256, 0, stream>>>(features, W_emb, b_emb, W_edge, edges,
                                         q, cursor64, flag);
    edge_scatter<<<(N_EDGESC + 512 * EPB - 1) / (512 * EPB), 512, 0, stream>>>(
        edges, noise, b_edge, q, cursor64, recS, recD, out, flag);
    gather_kernel<<<NBUCK_USED, 256, 0, stream>>>(recS, recD, cursor64, rS, rD,
                                                  out);
    final_kernel<<<(N_EDGESC + 1023) / 1024, 256, 0, stream>>>(edges, rS, rD,
                                                               out, flag);
}

// Round 7
// 259.789 us; speedup vs baseline: 1.0179x; 1.0127x over previous
//
#include <hip/hip_runtime.h>
#include <hip/hip_bf16.h>
#include <math.h>

#define N_NODESC 100000
#define N_EDGESC 1600000
#define IN_DIMC 256
#define HIDC 64
#define ALPHAC 0.1f
#define BIASC 1e-4f
#define EOSC 1e-10f

#define MC (N_EDGESC + N_NODESC)   // 1,700,000
#define NBUCK 400                  // buckets of 256 nodes (shift 8), per side
#define NBUCK_USED 391             // ceil(N_NODES / 256)
#define BSHIFT 8
#define BMASK 255
#define BCAP 5120u                 // expected ~4000/bucket, +17 sigma
#define W20SCALE 1048576.0f        // 2^20
#define W20INV (1.0f / 1048576.0f)
#define SUMMASK ((1ull << 40) - 1)
#define CNTONE (1ull << 40)
#define EPB 4                      // edges per thread in edge_scatter (512 thr)
#define NWAVE 8                    // waves per edge_scatter block

typedef __attribute__((ext_vector_type(8))) short short8;
typedef __attribute__((ext_vector_type(4))) float f32x4;

#define WT_STRIDE 264  // bf16 per j-row: 256 + 8 pad (528 B, 16B-aligned)

// edges may arrive as int32 (JAX x64-off) or int64 little-endian.
__device__ inline void load_edge(const int* __restrict__ edges, int e, int is64,
                                 int& src, int& dst) {
    if (is64) {
        const int2 a = ((const int2*)edges)[e];
        const int2 b = ((const int2*)edges)[N_EDGESC + e];
        src = a.x; dst = b.x;
    } else {
        src = edges[e];
        dst = edges[N_EDGESC + e];
    }
}

__device__ inline short pkbf(float x) {
    union { __hip_bfloat16 b; short s; } u;
    u.b = __float2bfloat16(x);
    return u.s;
}

// ---------------------------------------------------------------------------
// node kernel (MFMA): q[n] = relu(feat[n] @ W + b) @ (We[:64]+We[64:])
// 2 node-tiles per wave. Block 0 zeroes the packed u64 cursors + detects
// int32/int64 edge layout.
__global__ __launch_bounds__(256, 3) void node_kernel(
    const float* __restrict__ features,
    const float* __restrict__ W_emb,
    const float* __restrict__ b_emb,
    const float* __restrict__ W_edge,
    const int* __restrict__ edges,
    float* __restrict__ q,
    unsigned long long* __restrict__ cursor64,
    int* __restrict__ flag) {
    __shared__ __align__(16) short Wt[HIDC * WT_STRIDE];  // ~33.8 KB
    const int tid = threadIdx.x;
    if (blockIdx.x == 0) {
        if (tid == 0) {
            int z = 0;
            #pragma unroll
            for (int i = 0; i < 16; ++i) z |= edges[2 * i + 1];
            *flag = (z == 0) ? 1 : 0;  // 1 => int64 layout
        }
        for (int b = tid; b < NBUCK; b += 256) cursor64[b] = 0ull;
    }
    {
        const float4* Wg = (const float4*)W_emb;
        #pragma unroll
        for (int i = 0; i < 16; ++i) {
            const int f4 = tid + 256 * i;
            const float4 g = Wg[f4];
            const int flat = 4 * f4;
            const int k = flat >> 6;
            const int j0 = flat & 63;
            Wt[(j0 + 0) * WT_STRIDE + k] = pkbf(g.x);
            Wt[(j0 + 1) * WT_STRIDE + k] = pkbf(g.y);
            Wt[(j0 + 2) * WT_STRIDE + k] = pkbf(g.z);
            Wt[(j0 + 3) * WT_STRIDE + k] = pkbf(g.w);
        }
    }
    const int lane = tid & 63;
    const int wave = tid >> 6;
    const int quad = lane >> 4;
    const int m = lane & 15;
    f32x4 accA[4], accB[4];
    float wsum4[4];
    #pragma unroll
    for (int nt = 0; nt < 4; ++nt) {
        const int j = m + 16 * nt;
        const float b = b_emb[j];
        accA[nt] = (f32x4){b, b, b, b};
        accB[nt] = (f32x4){b, b, b, b};
        wsum4[nt] = W_edge[j] + W_edge[HIDC + j];
    }
    __syncthreads();

    const int node0A = blockIdx.x * 128 + wave * 16;
    const int node0B = node0A + 64;
    const float* frA = features + (size_t)min(node0A + m, N_NODESC - 1) * IN_DIMC;
    const float* frB = features + (size_t)min(node0B + m, N_NODESC - 1) * IN_DIMC;

    #pragma unroll
    for (int ks = 0; ks < 8; ++ks) {
        const int kk = ks * 32 + quad * 8;
        const float4 fa0 = *(const float4*)(frA + kk);
        const float4 fb0 = *(const float4*)(frA + kk + 4);
        const float4 fa1 = *(const float4*)(frB + kk);
        const float4 fb1 = *(const float4*)(frB + kk + 4);
        short8 afA, afB;
        afA[0] = pkbf(fa0.x); afA[1] = pkbf(fa0.y);
        afA[2] = pkbf(fa0.z); afA[3] = pkbf(fa0.w);
        afA[4] = pkbf(fb0.x); afA[5] = pkbf(fb0.y);
        afA[6] = pkbf(fb0.z); afA[7] = pkbf(fb0.w);
        afB[0] = pkbf(fa1.x); afB[1] = pkbf(fa1.y);
        afB[2] = pkbf(fa1.z); afB[3] = pkbf(fa1.w);
        afB[4] = pkbf(fb1.x); afB[5] = pkbf(fb1.y);
        afB[6] = pkbf(fb1.z); afB[7] = pkbf(fb1.w);
        #pragma unroll
        for (int nt = 0; nt < 4; ++nt) {
            const short8 bf =
                *(const short8*)&Wt[(m + 16 * nt) * WT_STRIDE + kk];
            accA[nt] = __builtin_amdgcn_mfma_f32_16x16x32_bf16(afA, bf, accA[nt],
                                                               0, 0, 0);
            accB[nt] = __builtin_amdgcn_mfma_f32_16x16x32_bf16(afB, bf, accB[nt],
                                                               0, 0, 0);
        }
    }

    #pragma unroll
    for (int r = 0; r < 4; ++r) {
        float sA = 0.f, sB = 0.f;
        #pragma unroll
        for (int nt = 0; nt < 4; ++nt) {
            sA = fmaf(fmaxf(accA[nt][r], 0.f), wsum4[nt], sA);
            sB = fmaf(fmaxf(accB[nt][r], 0.f), wsum4[nt], sB);
        }
        sA += __shfl_xor(sA, 1); sA += __shfl_xor(sA, 2);
        sA += __shfl_xor(sA, 4); sA += __shfl_xor(sA, 8);
        sB += __shfl_xor(sB, 1); sB += __shfl_xor(sB, 2);
        sB += __shfl_xor(sB, 4); sB += __shfl_xor(sB, 8);
        if (m == 0) {
            const int nA = node0A + quad * 4 + r;
            const int nB = node0B + quad * 4 + r;
            if (nA < N_NODESC) q[nA] = sA;
            if (nB < N_NODESC) q[nB] = sB;
        }
    }
}

// ---------------------------------------------------------------------------
// edge_scatter: 512 threads (8 waves), 4 edges/thread => 2048 edges/block,
// 782 blocks (3/CU, 24 waves/CU). Batched phases:
// all edge loads -> all q gathers -> compute+rank -> claim (ONE u64 atomic per
// bucket covers both sides, single pass) -> scatter.
// Records: u32 = (node_local_8b << 20) | wlp_fixed_20b, into ws bucket arrays.
__global__ __launch_bounds__(512) void edge_scatter(
    const int* __restrict__ edges,
    const float* __restrict__ noise,
    const float* __restrict__ b_edge,
    const float* __restrict__ q,
    unsigned long long* __restrict__ cursor64,
    unsigned* __restrict__ recS,
    unsigned* __restrict__ recD,
    float* __restrict__ out,
    const int* __restrict__ flag) {
    __shared__ unsigned hist[2][NWAVE][NBUCK];   // 25.6 KB
    __shared__ unsigned wbase[2][NWAVE][NBUCK];  // 25.6 KB
    const int tid = threadIdx.x;
    const int wave = tid >> 6;
    for (int i = tid; i < 2 * NWAVE * NBUCK; i += 512)
        ((unsigned*)hist)[i] = 0u;
    __syncthreads();
    const int is64 = *flag;
    const float be = b_edge[0];
    const int e0 = blockIdx.x * (512 * EPB) + tid;

    int sA[EPB], dA[EPB];
    #pragma unroll
    for (int i = 0; i < EPB; ++i) {
        const int e = e0 + i * 512;
        sA[i] = -1;
        if (e < N_EDGESC) load_edge(edges, e, is64, sA[i], dA[i]);
    }
    float qs[EPB], qd[EPB];
    #pragma unroll
    for (int i = 0; i < EPB; ++i) {
        if (sA[i] >= 0) { qs[i] = q[sA[i]]; qd[i] = q[dA[i]]; }
    }
    float wlpA[EPB];
    unsigned rkS[EPB], rkD[EPB];
    #pragma unroll
    for (int i = 0; i < EPB; ++i) {
        if (sA[i] >= 0) {
            const int e = e0 + i * 512;
            const float raw = 0.5f * (qs[i] + qd[i]) + be;
            const float u = noise[e];
            const float eps = (BIASC - (1.0f - BIASC)) * u + (1.0f - BIASC);
            const float gate = logf(eps) - log1pf(-eps);
            const float wlp = 1.0f / (1.0f + expf(-(gate + raw)));
            wlpA[i] = wlp;
            out[2 * MC + e] = wlp;
            out[2 * MC + N_EDGESC + e] = 1.0f - wlp;
            rkS[i] = atomicAdd(&hist[0][wave][sA[i] >> BSHIFT], 1u);
            rkD[i] = atomicAdd(&hist[1][wave][dA[i] >> BSHIFT], 1u);
        }
    }
    __syncthreads();
    // claim phase: single pass; one u64 atomic claims S (low 32) and D (high
    // 32) cursors for bucket tid.
    if (tid < NBUCK) {
        const int b = tid;
        unsigned ps[NWAVE], pd[NWAVE];
        unsigned totS = 0, totD = 0;
        #pragma unroll
        for (int w = 0; w < NWAVE; ++w) {
            ps[w] = totS; totS += hist[0][w][b];
            pd[w] = totD; totD += hist[1][w][b];
        }
        const unsigned long long add =
            (unsigned long long)totS | ((unsigned long long)totD << 32);
        const unsigned long long old = atomicAdd(&cursor64[b], add);
        const unsigned baseS = (unsigned)old;
        const unsigned baseD = (unsigned)(old >> 32);
        #pragma unroll
        for (int w = 0; w < NWAVE; ++w) {
            wbase[0][w][b] = baseS + ps[w];
            wbase[1][w][b] = baseD + pd[w];
        }
    }
    __syncthreads();
    #pragma unroll
    for (int i = 0; i < EPB; ++i) {
        if (sA[i] >= 0) {
            const int s = sA[i], d = dA[i];
            const unsigned w20 =
                min((unsigned)(wlpA[i] * W20SCALE + 0.5f), 0xFFFFFu);
            const unsigned pS = wbase[0][wave][s >> BSHIFT] + rkS[i];
            const unsigned pD = wbase[1][wave][d >> BSHIFT] + rkD[i];
            if (pS < BCAP)
                recS[(unsigned)(s >> BSHIFT) * BCAP + pS] =
                    ((unsigned)(s & BMASK) << 20) | w20;
            if (pD < BCAP)
                recD[(unsigned)(d >> BSHIFT) * BCAP + pD] =
                    ((unsigned)(d & BMASK) << 20) | w20;
        }
    }
}

// ---------------------------------------------------------------------------
// gather_kernel: 782 blocks; block owns ONE SIDE of one bucket
// (bid < 391 = S side, else D side). Records -> 256-entry LDS u64 table ->
// per-node float2 rsqrt pair.
__global__ __launch_bounds__(256) void gather_kernel(
    const unsigned* __restrict__ recS,
    const unsigned* __restrict__ recD,
    const unsigned long long* __restrict__ cursor64,
    float2* __restrict__ rS,
    float2* __restrict__ rD) {
    __shared__ unsigned long long table[256];
    const int bid = blockIdx.x;
    const int isD = bid >= NBUCK_USED;
    const int bkt = isD ? bid - NBUCK_USED : bid;
    const unsigned long long c = cursor64[bkt];
    const unsigned cnt = min((unsigned)(isD ? (c >> 32) : c), BCAP);
    const unsigned* rec = (isD ? recD : recS) + (unsigned)bkt * BCAP;
    const int tid = threadIdx.x;
    table[tid] = 0ull;
    __syncthreads();
    for (unsigned i = tid; i < cnt; i += 256) {
        const unsigned r = rec[i];
        atomicAdd(&table[r >> 20], CNTONE | (unsigned long long)(r & 0xFFFFFu));
    }
    __syncthreads();
    const int node = (bkt << BSHIFT) + tid;
    if (node < N_NODESC) {
        const unsigned long long a = table[tid];
        const float sum = (float)(a & SUMMASK) * W20INV;
        const float cf = (float)(a >> 40);
        float2 r;
        r.x = rsqrtf(1.0f + sum);        // lp degree (self-loop = 1)
        r.y = rsqrtf(1.0f + cf - sum);   // hp degree
        (isD ? rD : rS)[node] = r;
    }
}

// ---------------------------------------------------------------------------
// final kernel: 512 threads, 4 CONSECUTIVE elements/thread, fully vectorized:
// int4 edge loads, float4 wlp load, float4 stores to both output ranges.
// Covers [0, MC): edge range + self-loop tail (boundary 16B-aligned).
__global__ __launch_bounds__(512) void final_kernel(
    const int* __restrict__ edges,
    const float2* __restrict__ rS,
    const float2* __restrict__ rD,
    float* __restrict__ out,
    const int* __restrict__ flag) {
    const int i0 = (blockIdx.x * 512 + threadIdx.x) * 4;
    if (i0 >= MC) return;
    if (i0 + 4 <= N_EDGESC) {
        const int is64 = *flag;
        int s[4], d[4];
        if (is64) {
            const int4 a0 = ((const int4*)edges)[i0 >> 1];
            const int4 a1 = ((const int4*)edges)[(i0 >> 1) + 1];
            const int4 b0 = ((const int4*)edges)[(N_EDGESC + i0) >> 1];
            const int4 b1 = ((const int4*)edges)[((N_EDGESC + i0) >> 1) + 1];
            s[0] = a0.x; s[1] = a0.z; s[2] = a1.x; s[3] = a1.z;
            d[0] = b0.x; d[1] = b0.z; d[2] = b1.x; d[3] = b1.z;
        } else {
            const int4 a = ((const int4*)edges)[i0 >> 2];
            const int4 b = ((const int4*)edges)[(N_EDGESC + i0) >> 2];
            s[0] = a.x; s[1] = a.y; s[2] = a.z; s[3] = a.w;
            d[0] = b.x; d[1] = b.y; d[2] = b.z; d[3] = b.w;
        }
        const float4 w4 = *(const float4*)&out[2 * MC + i0];
        float2 av[4], bv[4];
        #pragma unroll
        for (int j = 0; j < 4; ++j) { av[j] = rS[s[j]]; bv[j] = rD[d[j]]; }
        const float wl[4] = {w4.x + EOSC, w4.y + EOSC, w4.z + EOSC, w4.w + EOSC};
        const float wh[4] = {(1.0f - w4.x) + EOSC, (1.0f - w4.y) + EOSC,
                             (1.0f - w4.z) + EOSC, (1.0f - w4.w) + EOSC};
        float4 o1, o2;
        o1.x = wl[0] * av[0].x * bv[0].x;
        o1.y = wl[1] * av[1].x * bv[1].x;
        o1.z = wl[2] * av[2].x * bv[2].x;
        o1.w = wl[3] * av[3].x * bv[3].x;
        o2.x = -ALPHAC * wh[0] * av[0].y * bv[0].y;
        o2.y = -ALPHAC * wh[1] * av[1].y * bv[1].y;
        o2.z = -ALPHAC * wh[2] * av[2].y * bv[2].y;
        o2.w = -ALPHAC * wh[3] * av[3].y * bv[3].y;
        *(float4*)&out[i0] = o1;
        *(float4*)&out[MC + i0] = o2;
    } else {
        // self-loop tail: i0 >= N_EDGESC (boundary divisible by 4)
        const int n0 = i0 - N_EDGESC;
        float4 o1;
        float* o1p = (float*)&o1;
        #pragma unroll
        for (int j = 0; j < 4; ++j) {
            const int n = n0 + j;
            o1p[j] = 0.f;
            if (n < N_NODESC) {
                const float2 a = rS[n];
                const float2 b = rD[n];
                o1p[j] = (1.0f + EOSC) * a.x * b.x;
            }
        }
        if (n0 + 4 <= N_NODESC) {
            *(float4*)&out[i0] = o1;
            *(float4*)&out[MC + i0] = (float4){1.f, 1.f, 1.f, 1.f};
        } else {
            #pragma unroll
            for (int j = 0; j < 4; ++j) {
                if (n0 + j < N_NODESC) {
                    out[i0 + j] = o1p[j];
                    out[MC + i0 + j] = 1.0f;
                }
            }
        }
    }
}

// ---------------------------------------------------------------------------
extern "C" void kernel_launch(void* const* d_in, const int* in_sizes, int n_in,
                              void* d_out, int out_size, void* d_ws, size_t ws_size,
                              hipStream_t stream) {
    const float* features = (const float*)d_in[0];
    const int* edges      = (const int*)d_in[1];
    const float* noise    = (const float*)d_in[2];
    const float* W_emb    = (const float*)d_in[3];
    const float* b_emb    = (const float*)d_in[4];
    const float* W_edge   = (const float*)d_in[5];
    const float* b_edge   = (const float*)d_in[6];
    float* out = (float*)d_out;
    char* ws = (char*)d_ws;

    // ws layout (bytes):
    //   [0, 400000)            q  : N f32
    //   [400000, 1200000)      rS : N float2
    //   [1200000, 2000000)     rD : N float2
    //   [2000000, 2000004)     flag
    //   [2000064, 2003264)     cursor64 : 400 u64 (S low 32 | D high 32)
    //   [2097152, 10289152)    recS : 400*5120 u32
    //   [10289152, 18481152)   recD : 400*5120 u32
    float* q = (float*)ws;
    float2* rS = (float2*)(ws + 400000);
    float2* rD = (float2*)(ws + 1200000);
    int* flag = (int*)(ws + 2000000);
    unsigned long long* cursor64 = (unsigned long long*)(ws + 2000064);
    unsigned* recS = (unsigned*)(ws + 2097152);
    unsigned* recD = (unsigned*)(ws + 10289152);

    node_kernel<<<782, 256, 0, stream>>>(features, W_emb, b_emb, W_edge, edges,
                                         q, cursor64, flag);
    edge_scatter<<<(N_EDGESC + 512 * EPB - 1) / (512 * EPB), 512, 0, stream>>>(
        edges, noise, b_edge, q, cursor64, recS, recD, out, flag);
    gather_kernel<<<2 * NBUCK_USED, 256, 0, stream>>>(recS, recD, cursor64, rS,
                                                      rD);
    final_kernel<<<(MC / 4 + 511) / 512, 512, 0, stream>>>(edges, rS, rD, out,
                                                           flag);
}

// Round 8
// 252.543 us; speedup vs baseline: 1.0471x; 1.0287x over previous
//
#include <hip/hip_runtime.h>
#include <hip/hip_bf16.h>
#include <math.h>

#define N_NODESC 100000
#define N_EDGESC 1600000
#define IN_DIMC 256
#define HIDC 64
#define ALPHAC 0.1f
#define BIASC 1e-4f
#define EOSC 1e-10f

#define MC (N_EDGESC + N_NODESC)   // 1,700,000
#define NBUCK 400                  // buckets of 256 nodes (shift 8), per side
#define NBUCK_USED 391             // ceil(N_NODES / 256)
#define BSHIFT 8
#define BMASK 255
#define BCAP 5120u                 // expected ~4000/bucket, +17 sigma
#define W20SCALE 1048576.0f        // 2^20
#define W20INV (1.0f / 1048576.0f)
#define SUMMASK ((1ull << 40) - 1)
#define CNTONE (1ull << 40)
#define NWAVE 8                    // waves per edge_scatter block

typedef __attribute__((ext_vector_type(8))) short short8;
typedef __attribute__((ext_vector_type(4))) float f32x4;

#define WT_STRIDE 264  // bf16 per j-row: 256 + 8 pad (528 B, 16B-aligned)

__device__ inline short pkbf(float x) {
    union { __hip_bfloat16 b; short s; } u;
    u.b = __float2bfloat16(x);
    return u.s;
}

// ---------------------------------------------------------------------------
// node kernel (MFMA): q[n] = relu(feat[n] @ W + b) @ (We[:64]+We[64:])
// 2 node-tiles per wave. Block 0 zeroes the packed u64 cursors + detects
// int32/int64 edge layout.
__global__ __launch_bounds__(256, 3) void node_kernel(
    const float* __restrict__ features,
    const float* __restrict__ W_emb,
    const float* __restrict__ b_emb,
    const float* __restrict__ W_edge,
    const int* __restrict__ edges,
    float* __restrict__ q,
    unsigned long long* __restrict__ cursor64,
    int* __restrict__ flag) {
    __shared__ __align__(16) short Wt[HIDC * WT_STRIDE];  // ~33.8 KB
    const int tid = threadIdx.x;
    if (blockIdx.x == 0) {
        if (tid == 0) {
            int z = 0;
            #pragma unroll
            for (int i = 0; i < 16; ++i) z |= edges[2 * i + 1];
            *flag = (z == 0) ? 1 : 0;  // 1 => int64 layout
        }
        for (int b = tid; b < NBUCK; b += 256) cursor64[b] = 0ull;
    }
    {
        const float4* Wg = (const float4*)W_emb;
        #pragma unroll
        for (int i = 0; i < 16; ++i) {
            const int f4 = tid + 256 * i;
            const float4 g = Wg[f4];
            const int flat = 4 * f4;
            const int k = flat >> 6;
            const int j0 = flat & 63;
            Wt[(j0 + 0) * WT_STRIDE + k] = pkbf(g.x);
            Wt[(j0 + 1) * WT_STRIDE + k] = pkbf(g.y);
            Wt[(j0 + 2) * WT_STRIDE + k] = pkbf(g.z);
            Wt[(j0 + 3) * WT_STRIDE + k] = pkbf(g.w);
        }
    }
    const int lane = tid & 63;
    const int wave = tid >> 6;
    const int quad = lane >> 4;
    const int m = lane & 15;
    f32x4 accA[4], accB[4];
    float wsum4[4];
    #pragma unroll
    for (int nt = 0; nt < 4; ++nt) {
        const int j = m + 16 * nt;
        const float b = b_emb[j];
        accA[nt] = (f32x4){b, b, b, b};
        accB[nt] = (f32x4){b, b, b, b};
        wsum4[nt] = W_edge[j] + W_edge[HIDC + j];
    }
    __syncthreads();

    const int node0A = blockIdx.x * 128 + wave * 16;
    const int node0B = node0A + 64;
    const float* frA = features + (size_t)min(node0A + m, N_NODESC - 1) * IN_DIMC;
    const float* frB = features + (size_t)min(node0B + m, N_NODESC - 1) * IN_DIMC;

    #pragma unroll
    for (int ks = 0; ks < 8; ++ks) {
        const int kk = ks * 32 + quad * 8;
        const float4 fa0 = *(const float4*)(frA + kk);
        const float4 fb0 = *(const float4*)(frA + kk + 4);
        const float4 fa1 = *(const float4*)(frB + kk);
        const float4 fb1 = *(const float4*)(frB + kk + 4);
        short8 afA, afB;
        afA[0] = pkbf(fa0.x); afA[1] = pkbf(fa0.y);
        afA[2] = pkbf(fa0.z); afA[3] = pkbf(fa0.w);
        afA[4] = pkbf(fb0.x); afA[5] = pkbf(fb0.y);
        afA[6] = pkbf(fb0.z); afA[7] = pkbf(fb0.w);
        afB[0] = pkbf(fa1.x); afB[1] = pkbf(fa1.y);
        afB[2] = pkbf(fa1.z); afB[3] = pkbf(fa1.w);
        afB[4] = pkbf(fb1.x); afB[5] = pkbf(fb1.y);
        afB[6] = pkbf(fb1.z); afB[7] = pkbf(fb1.w);
        #pragma unroll
        for (int nt = 0; nt < 4; ++nt) {
            const short8 bf =
                *(const short8*)&Wt[(m + 16 * nt) * WT_STRIDE + kk];
            accA[nt] = __builtin_amdgcn_mfma_f32_16x16x32_bf16(afA, bf, accA[nt],
                                                               0, 0, 0);
            accB[nt] = __builtin_amdgcn_mfma_f32_16x16x32_bf16(afB, bf, accB[nt],
                                                               0, 0, 0);
        }
    }

    #pragma unroll
    for (int r = 0; r < 4; ++r) {
        float sA = 0.f, sB = 0.f;
        #pragma unroll
        for (int nt = 0; nt < 4; ++nt) {
            sA = fmaf(fmaxf(accA[nt][r], 0.f), wsum4[nt], sA);
            sB = fmaf(fmaxf(accB[nt][r], 0.f), wsum4[nt], sB);
        }
        sA += __shfl_xor(sA, 1); sA += __shfl_xor(sA, 2);
        sA += __shfl_xor(sA, 4); sA += __shfl_xor(sA, 8);
        sB += __shfl_xor(sB, 1); sB += __shfl_xor(sB, 2);
        sB += __shfl_xor(sB, 4); sB += __shfl_xor(sB, 8);
        if (m == 0) {
            const int nA = node0A + quad * 4 + r;
            const int nB = node0B + quad * 4 + r;
            if (nA < N_NODESC) q[nA] = sA;
            if (nB < N_NODESC) q[nB] = sB;
        }
    }
}

// ---------------------------------------------------------------------------
// edge_scatter: 512 threads (8 waves), 4 CONSECUTIVE edges/thread => 2048
// edges/block, 782 blocks (3/CU). Vectorized coalesced IO: int4 edge loads,
// float4 noise load, float4 wlp/whp stores. Batched phases:
// loads -> q gathers -> compute+rank -> claim (one u64 atomic per bucket,
// both sides) -> record scatter.
// Records: u32 = (node_local_8b << 20) | wlp_fixed_20b, into ws bucket arrays.
__global__ __launch_bounds__(512) void edge_scatter(
    const int* __restrict__ edges,
    const float* __restrict__ noise,
    const float* __restrict__ b_edge,
    const float* __restrict__ q,
    unsigned long long* __restrict__ cursor64,
    unsigned* __restrict__ recS,
    unsigned* __restrict__ recD,
    float* __restrict__ out,
    const int* __restrict__ flag) {
    __shared__ unsigned hist[2][NWAVE][NBUCK];   // 25.6 KB
    __shared__ unsigned wbase[2][NWAVE][NBUCK];  // 25.6 KB
    const int tid = threadIdx.x;
    const int wave = tid >> 6;
    for (int i = tid; i < 2 * NWAVE * NBUCK; i += 512)
        ((unsigned*)hist)[i] = 0u;
    __syncthreads();
    const int is64 = *flag;
    const float be = b_edge[0];
    const int e4 = (blockIdx.x * 512 + tid) * 4;  // 4 consecutive edges
    const bool act = e4 < N_EDGESC;               // N_EDGES % 4 == 0

    int s[4], d[4];
    float wlp[4];
    unsigned rkS[4], rkD[4];
    if (act) {
        if (is64) {
            const int4 a0 = ((const int4*)edges)[e4 >> 1];
            const int4 a1 = ((const int4*)edges)[(e4 >> 1) + 1];
            const int4 b0 = ((const int4*)edges)[(N_EDGESC + e4) >> 1];
            const int4 b1 = ((const int4*)edges)[((N_EDGESC + e4) >> 1) + 1];
            s[0] = a0.x; s[1] = a0.z; s[2] = a1.x; s[3] = a1.z;
            d[0] = b0.x; d[1] = b0.z; d[2] = b1.x; d[3] = b1.z;
        } else {
            const int4 a = ((const int4*)edges)[e4 >> 2];
            const int4 b = ((const int4*)edges)[(N_EDGESC + e4) >> 2];
            s[0] = a.x; s[1] = a.y; s[2] = a.z; s[3] = a.w;
            d[0] = b.x; d[1] = b.y; d[2] = b.z; d[3] = b.w;
        }
        float qs[4], qd[4];
        #pragma unroll
        for (int i = 0; i < 4; ++i) { qs[i] = q[s[i]]; qd[i] = q[d[i]]; }
        const float4 u4 = *(const float4*)&noise[e4];
        const float un[4] = {u4.x, u4.y, u4.z, u4.w};
        float4 owl, owh;
        float* owlp = (float*)&owl;
        float* owhp = (float*)&owh;
        #pragma unroll
        for (int i = 0; i < 4; ++i) {
            const float raw = 0.5f * (qs[i] + qd[i]) + be;
            const float eps = (BIASC - (1.0f - BIASC)) * un[i] + (1.0f - BIASC);
            const float gate = logf(eps) - log1pf(-eps);
            const float w = 1.0f / (1.0f + expf(-(gate + raw)));
            wlp[i] = w;
            owlp[i] = w;
            owhp[i] = 1.0f - w;
        }
        *(float4*)&out[2 * MC + e4] = owl;
        *(float4*)&out[2 * MC + N_EDGESC + e4] = owh;
        #pragma unroll
        for (int i = 0; i < 4; ++i) {
            rkS[i] = atomicAdd(&hist[0][wave][s[i] >> BSHIFT], 1u);
            rkD[i] = atomicAdd(&hist[1][wave][d[i] >> BSHIFT], 1u);
        }
    }
    __syncthreads();
    // claim phase: one u64 atomic claims S (low 32) and D (high 32) cursors.
    if (tid < NBUCK) {
        const int b = tid;
        unsigned ps[NWAVE], pd[NWAVE];
        unsigned totS = 0, totD = 0;
        #pragma unroll
        for (int w = 0; w < NWAVE; ++w) {
            ps[w] = totS; totS += hist[0][w][b];
            pd[w] = totD; totD += hist[1][w][b];
        }
        const unsigned long long add =
            (unsigned long long)totS | ((unsigned long long)totD << 32);
        const unsigned long long old = atomicAdd(&cursor64[b], add);
        const unsigned baseS = (unsigned)old;
        const unsigned baseD = (unsigned)(old >> 32);
        #pragma unroll
        for (int w = 0; w < NWAVE; ++w) {
            wbase[0][w][b] = baseS + ps[w];
            wbase[1][w][b] = baseD + pd[w];
        }
    }
    __syncthreads();
    if (act) {
        #pragma unroll
        for (int i = 0; i < 4; ++i) {
            const unsigned w20 =
                min((unsigned)(wlp[i] * W20SCALE + 0.5f), 0xFFFFFu);
            const unsigned pS = wbase[0][wave][s[i] >> BSHIFT] + rkS[i];
            const unsigned pD = wbase[1][wave][d[i] >> BSHIFT] + rkD[i];
            if (pS < BCAP)
                recS[(unsigned)(s[i] >> BSHIFT) * BCAP + pS] =
                    ((unsigned)(s[i] & BMASK) << 20) | w20;
            if (pD < BCAP)
                recD[(unsigned)(d[i] >> BSHIFT) * BCAP + pD] =
                    ((unsigned)(d[i] & BMASK) << 20) | w20;
        }
    }
}

// ---------------------------------------------------------------------------
// gather_kernel: 782 blocks; block owns ONE SIDE of one bucket
// (bid < 391 = S side, else D side). uint4-vectorized record reads ->
// 256-entry LDS u64 table -> per-node float2 rsqrt pair.
__global__ __launch_bounds__(256) void gather_kernel(
    const unsigned* __restrict__ recS,
    const unsigned* __restrict__ recD,
    const unsigned long long* __restrict__ cursor64,
    float2* __restrict__ rS,
    float2* __restrict__ rD) {
    __shared__ unsigned long long table[256];
    const int bid = blockIdx.x;
    const int isD = bid >= NBUCK_USED;
    const int bkt = isD ? bid - NBUCK_USED : bid;
    const unsigned long long c = cursor64[bkt];
    const unsigned cnt = min((unsigned)(isD ? (c >> 32) : c), BCAP);
    const unsigned* rec = (isD ? recD : recS) + (unsigned)bkt * BCAP;
    const int tid = threadIdx.x;
    table[tid] = 0ull;
    __syncthreads();
    const unsigned cnt4 = cnt & ~3u;
    for (unsigned i = tid * 4; i < cnt4; i += 1024) {
        const uint4 r4 = *(const uint4*)&rec[i];
        atomicAdd(&table[r4.x >> 20], CNTONE | (unsigned long long)(r4.x & 0xFFFFFu));
        atomicAdd(&table[r4.y >> 20], CNTONE | (unsigned long long)(r4.y & 0xFFFFFu));
        atomicAdd(&table[r4.z >> 20], CNTONE | (unsigned long long)(r4.z & 0xFFFFFu));
        atomicAdd(&table[r4.w >> 20], CNTONE | (unsigned long long)(r4.w & 0xFFFFFu));
    }
    {
        const unsigned i = cnt4 + tid;
        if (i < cnt) {
            const unsigned r = rec[i];
            atomicAdd(&table[r >> 20],
                      CNTONE | (unsigned long long)(r & 0xFFFFFu));
        }
    }
    __syncthreads();
    const int node = (bkt << BSHIFT) + tid;
    if (node < N_NODESC) {
        const unsigned long long a = table[tid];
        const float sum = (float)(a & SUMMASK) * W20INV;
        const float cf = (float)(a >> 40);
        float2 r;
        r.x = rsqrtf(1.0f + sum);        // lp degree (self-loop = 1)
        r.y = rsqrtf(1.0f + cf - sum);   // hp degree
        (isD ? rD : rS)[node] = r;
    }
}

// ---------------------------------------------------------------------------
// final kernel: 512 threads, 4 CONSECUTIVE elements/thread, fully vectorized:
// int4 edge loads, float4 wlp load, float4 stores to both output ranges.
// Covers [0, MC): edge range + self-loop tail (boundary 16B-aligned).
__global__ __launch_bounds__(512) void final_kernel(
    const int* __restrict__ edges,
    const float2* __restrict__ rS,
    const float2* __restrict__ rD,
    float* __restrict__ out,
    const int* __restrict__ flag) {
    const int i0 = (blockIdx.x * 512 + threadIdx.x) * 4;
    if (i0 >= MC) return;
    if (i0 + 4 <= N_EDGESC) {
        const int is64 = *flag;
        int s[4], d[4];
        if (is64) {
            const int4 a0 = ((const int4*)edges)[i0 >> 1];
            const int4 a1 = ((const int4*)edges)[(i0 >> 1) + 1];
            const int4 b0 = ((const int4*)edges)[(N_EDGESC + i0) >> 1];
            const int4 b1 = ((const int4*)edges)[((N_EDGESC + i0) >> 1) + 1];
            s[0] = a0.x; s[1] = a0.z; s[2] = a1.x; s[3] = a1.z;
            d[0] = b0.x; d[1] = b0.z; d[2] = b1.x; d[3] = b1.z;
        } else {
            const int4 a = ((const int4*)edges)[i0 >> 2];
            const int4 b = ((const int4*)edges)[(N_EDGESC + i0) >> 2];
            s[0] = a.x; s[1] = a.y; s[2] = a.z; s[3] = a.w;
            d[0] = b.x; d[1] = b.y; d[2] = b.z; d[3] = b.w;
        }
        const float4 w4 = *(const float4*)&out[2 * MC + i0];
        float2 av[4], bv[4];
        #pragma unroll
        for (int j = 0; j < 4; ++j) { av[j] = rS[s[j]]; bv[j] = rD[d[j]]; }
        const float wl[4] = {w4.x + EOSC, w4.y + EOSC, w4.z + EOSC, w4.w + EOSC};
        const float wh[4] = {(1.0f - w4.x) + EOSC, (1.0f - w4.y) + EOSC,
                             (1.0f - w4.z) + EOSC, (1.0f - w4.w) + EOSC};
        float4 o1, o2;
        o1.x = wl[0] * av[0].x * bv[0].x;
        o1.y = wl[1] * av[1].x * bv[1].x;
        o1.z = wl[2] * av[2].x * bv[2].x;
        o1.w = wl[3] * av[3].x * bv[3].x;
        o2.x = -ALPHAC * wh[0] * av[0].y * bv[0].y;
        o2.y = -ALPHAC * wh[1] * av[1].y * bv[1].y;
        o2.z = -ALPHAC * wh[2] * av[2].y * bv[2].y;
        o2.w = -ALPHAC * wh[3] * av[3].y * bv[3].y;
        *(float4*)&out[i0] = o1;
        *(float4*)&out[MC + i0] = o2;
    } else {
        // self-loop tail: i0 >= N_EDGESC (boundary divisible by 4)
        const int n0 = i0 - N_EDGESC;
        float4 o1;
        float* o1p = (float*)&o1;
        #pragma unroll
        for (int j = 0; j < 4; ++j) {
            const int n = n0 + j;
            o1p[j] = 0.f;
            if (n < N_NODESC) {
                const float2 a = rS[n];
                const float2 b = rD[n];
                o1p[j] = (1.0f + EOSC) * a.x * b.x;
            }
        }
        if (n0 + 4 <= N_NODESC) {
            *(float4*)&out[i0] = o1;
            *(float4*)&out[MC + i0] = (float4){1.f, 1.f, 1.f, 1.f};
        } else {
            #pragma unroll
            for (int j = 0; j < 4; ++j) {
                if (n0 + j < N_NODESC) {
                    out[i0 + j] = o1p[j];
                    out[MC + i0 + j] = 1.0f;
                }
            }
        }
    }
}

// ---------------------------------------------------------------------------
extern "C" void kernel_launch(void* const* d_in, const int* in_sizes, int n_in,
                              void* d_out, int out_size, void* d_ws, size_t ws_size,
                              hipStream_t stream) {
    const float* features = (const float*)d_in[0];
    const int* edges      = (const int*)d_in[1];
    const float* noise    = (const float*)d_in[2];
    const float* W_emb    = (const float*)d_in[3];
    const float* b_emb    = (const float*)d_in[4];
    const float* W_edge   = (const float*)d_in[5];
    const float* b_edge   = (const float*)d_in[6];
    float* out = (float*)d_out;
    char* ws = (char*)d_ws;

    // ws layout (bytes):
    //   [0, 400000)            q  : N f32
    //   [400000, 1200000)      rS : N float2
    //   [1200000, 2000000)     rD : N float2
    //   [2000000, 2000004)     flag
    //   [2000064, 2003264)     cursor64 : 400 u64 (S low 32 | D high 32)
    //   [2097152, 10289152)    recS : 400*5120 u32
    //   [10289152, 18481152)   recD : 400*5120 u32
    float* q = (float*)ws;
    float2* rS = (float2*)(ws + 400000);
    float2* rD = (float2*)(ws + 1200000);
    int* flag = (int*)(ws + 2000000);
    unsigned long long* cursor64 = (unsigned long long*)(ws + 2000064);
    unsigned* recS = (unsigned*)(ws + 2097152);
    unsigned* recD = (unsigned*)(ws + 10289152);

    node_kernel<<<782, 256, 0, stream>>>(features, W_emb, b_emb, W_edge, edges,
                                         q, cursor64, flag);
    edge_scatter<<<(N_EDGESC / 4 + 511) / 512, 512, 0, stream>>>(
        edges, noise, b_edge, q, cursor64, recS, recD, out, flag);
    gather_kernel<<<2 * NBUCK_USED, 256, 0, stream>>>(recS, recD, cursor64, rS,
                                                      rD);
    final_kernel<<<(MC / 4 + 511) / 512, 512, 0, stream>>>(edges, rS, rD, out,
                                                           flag);
}

// Round 9
// 250.057 us; speedup vs baseline: 1.0575x; 1.0099x over previous
//
#include <hip/hip_runtime.h>
#include <hip/hip_bf16.h>
#include <math.h>

#define N_NODESC 100000
#define N_EDGESC 1600000
#define IN_DIMC 256
#define HIDC 64
#define ALPHAC 0.1f
#define BIASC 1e-4f
#define EOSC 1e-10f

#define MC (N_EDGESC + N_NODESC)   // 1,700,000
#define NBUCK 400                  // buckets of 256 nodes (shift 8), per side
#define NBUCK_USED 391             // ceil(N_NODES / 256)
#define BSHIFT 8
#define BMASK 255
#define BCAP 5120u                 // expected ~4000/bucket, +17 sigma
#define W20SCALE 1048576.0f        // 2^20
#define W20INV (1.0f / 1048576.0f)
#define SUMMASK ((1ull << 40) - 1)
#define CNTONE (1ull << 40)
#define NWAVE 8                    // waves per edge_scatter block

typedef __attribute__((ext_vector_type(8))) short short8;
typedef __attribute__((ext_vector_type(4))) float f32x4;

#define WT_STRIDE 264  // bf16 per j-row: 256 + 8 pad (528 B, 16B-aligned)

__device__ inline short pkbf(float x) {
    union { __hip_bfloat16 b; short s; } u;
    u.b = __float2bfloat16(x);
    return u.s;
}

// ---------------------------------------------------------------------------
// node kernel (MFMA): q[n] = relu(feat[n] @ W + b) @ (We[:64]+We[64:])
// 2 node-tiles per wave. Block 0 zeroes the packed u64 cursors + detects
// int32/int64 edge layout.
__global__ __launch_bounds__(256, 3) void node_kernel(
    const float* __restrict__ features,
    const float* __restrict__ W_emb,
    const float* __restrict__ b_emb,
    const float* __restrict__ W_edge,
    const int* __restrict__ edges,
    float* __restrict__ q,
    unsigned long long* __restrict__ cursor64,
    int* __restrict__ flag) {
    __shared__ __align__(16) short Wt[HIDC * WT_STRIDE];  // ~33.8 KB
    const int tid = threadIdx.x;
    if (blockIdx.x == 0) {
        if (tid == 0) {
            int z = 0;
            #pragma unroll
            for (int i = 0; i < 16; ++i) z |= edges[2 * i + 1];
            *flag = (z == 0) ? 1 : 0;  // 1 => int64 layout
        }
        for (int b = tid; b < NBUCK; b += 256) cursor64[b] = 0ull;
    }
    {
        const float4* Wg = (const float4*)W_emb;
        #pragma unroll
        for (int i = 0; i < 16; ++i) {
            const int f4 = tid + 256 * i;
            const float4 g = Wg[f4];
            const int flat = 4 * f4;
            const int k = flat >> 6;
            const int j0 = flat & 63;
            Wt[(j0 + 0) * WT_STRIDE + k] = pkbf(g.x);
            Wt[(j0 + 1) * WT_STRIDE + k] = pkbf(g.y);
            Wt[(j0 + 2) * WT_STRIDE + k] = pkbf(g.z);
            Wt[(j0 + 3) * WT_STRIDE + k] = pkbf(g.w);
        }
    }
    const int lane = tid & 63;
    const int wave = tid >> 6;
    const int quad = lane >> 4;
    const int m = lane & 15;
    f32x4 accA[4], accB[4];
    float wsum4[4];
    #pragma unroll
    for (int nt = 0; nt < 4; ++nt) {
        const int j = m + 16 * nt;
        const float b = b_emb[j];
        accA[nt] = (f32x4){b, b, b, b};
        accB[nt] = (f32x4){b, b, b, b};
        wsum4[nt] = W_edge[j] + W_edge[HIDC + j];
    }
    __syncthreads();

    const int node0A = blockIdx.x * 128 + wave * 16;
    const int node0B = node0A + 64;
    const float* frA = features + (size_t)min(node0A + m, N_NODESC - 1) * IN_DIMC;
    const float* frB = features + (size_t)min(node0B + m, N_NODESC - 1) * IN_DIMC;

    #pragma unroll
    for (int ks = 0; ks < 8; ++ks) {
        const int kk = ks * 32 + quad * 8;
        const float4 fa0 = *(const float4*)(frA + kk);
        const float4 fb0 = *(const float4*)(frA + kk + 4);
        const float4 fa1 = *(const float4*)(frB + kk);
        const float4 fb1 = *(const float4*)(frB + kk + 4);
        short8 afA, afB;
        afA[0] = pkbf(fa0.x); afA[1] = pkbf(fa0.y);
        afA[2] = pkbf(fa0.z); afA[3] = pkbf(fa0.w);
        afA[4] = pkbf(fb0.x); afA[5] = pkbf(fb0.y);
        afA[6] = pkbf(fb0.z); afA[7] = pkbf(fb0.w);
        afB[0] = pkbf(fa1.x); afB[1] = pkbf(fa1.y);
        afB[2] = pkbf(fa1.z); afB[3] = pkbf(fa1.w);
        afB[4] = pkbf(fb1.x); afB[5] = pkbf(fb1.y);
        afB[6] = pkbf(fb1.z); afB[7] = pkbf(fb1.w);
        #pragma unroll
        for (int nt = 0; nt < 4; ++nt) {
            const short8 bf =
                *(const short8*)&Wt[(m + 16 * nt) * WT_STRIDE + kk];
            accA[nt] = __builtin_amdgcn_mfma_f32_16x16x32_bf16(afA, bf, accA[nt],
                                                               0, 0, 0);
            accB[nt] = __builtin_amdgcn_mfma_f32_16x16x32_bf16(afB, bf, accB[nt],
                                                               0, 0, 0);
        }
    }

    #pragma unroll
    for (int r = 0; r < 4; ++r) {
        float sA = 0.f, sB = 0.f;
        #pragma unroll
        for (int nt = 0; nt < 4; ++nt) {
            sA = fmaf(fmaxf(accA[nt][r], 0.f), wsum4[nt], sA);
            sB = fmaf(fmaxf(accB[nt][r], 0.f), wsum4[nt], sB);
        }
        sA += __shfl_xor(sA, 1); sA += __shfl_xor(sA, 2);
        sA += __shfl_xor(sA, 4); sA += __shfl_xor(sA, 8);
        sB += __shfl_xor(sB, 1); sB += __shfl_xor(sB, 2);
        sB += __shfl_xor(sB, 4); sB += __shfl_xor(sB, 8);
        if (m == 0) {
            const int nA = node0A + quad * 4 + r;
            const int nB = node0B + quad * 4 + r;
            if (nA < N_NODESC) q[nA] = sA;
            if (nB < N_NODESC) q[nB] = sB;
        }
    }
}

// ---------------------------------------------------------------------------
// edge_scatter: 512 threads (8 waves), 4 CONSECUTIVE edges/thread => 2048
// edges/block, 782 blocks (3/CU). Vectorized coalesced IO: int4 edge loads,
// float4 noise load, float4 wlp/whp stores. Batched phases:
// loads -> q gathers -> compute+rank -> claim (one u64 atomic per bucket,
// both sides) -> record scatter.
// wlp uses the logit identity sigmoid(log(eps/(1-eps)) + raw)
//   = eps / (eps + (1-eps)*exp(-raw))  -- no logf/log1pf on the chain.
// Records: u32 = (node_local_8b << 20) | wlp_fixed_20b, into ws bucket arrays.
__global__ __launch_bounds__(512) void edge_scatter(
    const int* __restrict__ edges,
    const float* __restrict__ noise,
    const float* __restrict__ b_edge,
    const float* __restrict__ q,
    unsigned long long* __restrict__ cursor64,
    unsigned* __restrict__ recS,
    unsigned* __restrict__ recD,
    float* __restrict__ out,
    const int* __restrict__ flag) {
    __shared__ unsigned hist[2][NWAVE][NBUCK];   // 25.6 KB
    __shared__ unsigned wbase[2][NWAVE][NBUCK];  // 25.6 KB
    const int tid = threadIdx.x;
    const int wave = tid >> 6;
    {
        uint4* hz = (uint4*)hist;  // 2*8*400/4 = 1600 uint4
        const uint4 z4 = {0u, 0u, 0u, 0u};
        #pragma unroll
        for (int i = 0; i < 4; ++i) {
            const int idx = tid + i * 512;
            if (idx < 1600) hz[idx] = z4;
        }
    }
    __syncthreads();
    const int is64 = *flag;
    const float be = b_edge[0];
    const int e4 = (blockIdx.x * 512 + tid) * 4;  // 4 consecutive edges
    const bool act = e4 < N_EDGESC;               // N_EDGES % 4 == 0

    int s[4], d[4];
    float wlp[4];
    unsigned rkS[4], rkD[4];
    if (act) {
        if (is64) {
            const int4 a0 = ((const int4*)edges)[e4 >> 1];
            const int4 a1 = ((const int4*)edges)[(e4 >> 1) + 1];
            const int4 b0 = ((const int4*)edges)[(N_EDGESC + e4) >> 1];
            const int4 b1 = ((const int4*)edges)[((N_EDGESC + e4) >> 1) + 1];
            s[0] = a0.x; s[1] = a0.z; s[2] = a1.x; s[3] = a1.z;
            d[0] = b0.x; d[1] = b0.z; d[2] = b1.x; d[3] = b1.z;
        } else {
            const int4 a = ((const int4*)edges)[e4 >> 2];
            const int4 b = ((const int4*)edges)[(N_EDGESC + e4) >> 2];
            s[0] = a.x; s[1] = a.y; s[2] = a.z; s[3] = a.w;
            d[0] = b.x; d[1] = b.y; d[2] = b.z; d[3] = b.w;
        }
        float qs[4], qd[4];
        #pragma unroll
        for (int i = 0; i < 4; ++i) { qs[i] = q[s[i]]; qd[i] = q[d[i]]; }
        const float4 u4 = *(const float4*)&noise[e4];
        const float un[4] = {u4.x, u4.y, u4.z, u4.w};
        float4 owl, owh;
        float* owlp = (float*)&owl;
        float* owhp = (float*)&owh;
        #pragma unroll
        for (int i = 0; i < 4; ++i) {
            const float raw = 0.5f * (qs[i] + qd[i]) + be;
            const float eps = (BIASC - (1.0f - BIASC)) * un[i] + (1.0f - BIASC);
            // sigmoid(logit(eps) + raw) without logf/log1pf:
            const float w = eps / (eps + (1.0f - eps) * expf(-raw));
            wlp[i] = w;
            owlp[i] = w;
            owhp[i] = 1.0f - w;
        }
        *(float4*)&out[2 * MC + e4] = owl;
        *(float4*)&out[2 * MC + N_EDGESC + e4] = owh;
        #pragma unroll
        for (int i = 0; i < 4; ++i) {
            rkS[i] = atomicAdd(&hist[0][wave][s[i] >> BSHIFT], 1u);
            rkD[i] = atomicAdd(&hist[1][wave][d[i] >> BSHIFT], 1u);
        }
    }
    __syncthreads();
    // claim phase: one u64 atomic claims S (low 32) and D (high 32) cursors.
    if (tid < NBUCK) {
        const int b = tid;
        unsigned ps[NWAVE], pd[NWAVE];
        unsigned totS = 0, totD = 0;
        #pragma unroll
        for (int w = 0; w < NWAVE; ++w) {
            ps[w] = totS; totS += hist[0][w][b];
            pd[w] = totD; totD += hist[1][w][b];
        }
        const unsigned long long add =
            (unsigned long long)totS | ((unsigned long long)totD << 32);
        const unsigned long long old = atomicAdd(&cursor64[b], add);
        const unsigned baseS = (unsigned)old;
        const unsigned baseD = (unsigned)(old >> 32);
        #pragma unroll
        for (int w = 0; w < NWAVE; ++w) {
            wbase[0][w][b] = baseS + ps[w];
            wbase[1][w][b] = baseD + pd[w];
        }
    }
    __syncthreads();
    if (act) {
        #pragma unroll
        for (int i = 0; i < 4; ++i) {
            const unsigned w20 =
                min((unsigned)(wlp[i] * W20SCALE + 0.5f), 0xFFFFFu);
            const unsigned pS = wbase[0][wave][s[i] >> BSHIFT] + rkS[i];
            const unsigned pD = wbase[1][wave][d[i] >> BSHIFT] + rkD[i];
            if (pS < BCAP)
                recS[(unsigned)(s[i] >> BSHIFT) * BCAP + pS] =
                    ((unsigned)(s[i] & BMASK) << 20) | w20;
            if (pD < BCAP)
                recD[(unsigned)(d[i] >> BSHIFT) * BCAP + pD] =
                    ((unsigned)(d[i] & BMASK) << 20) | w20;
        }
    }
}

// ---------------------------------------------------------------------------
// gather_kernel: 782 blocks; block owns ONE SIDE of one bucket
// (bid < 391 = S side, else D side). uint4-vectorized record reads ->
// 256-entry LDS u64 table -> per-node float2 rsqrt pair.
__global__ __launch_bounds__(256) void gather_kernel(
    const unsigned* __restrict__ recS,
    const unsigned* __restrict__ recD,
    const unsigned long long* __restrict__ cursor64,
    float2* __restrict__ rS,
    float2* __restrict__ rD) {
    __shared__ unsigned long long table[256];
    const int bid = blockIdx.x;
    const int isD = bid >= NBUCK_USED;
    const int bkt = isD ? bid - NBUCK_USED : bid;
    const unsigned long long c = cursor64[bkt];
    const unsigned cnt = min((unsigned)(isD ? (c >> 32) : c), BCAP);
    const unsigned* rec = (isD ? recD : recS) + (unsigned)bkt * BCAP;
    const int tid = threadIdx.x;
    table[tid] = 0ull;
    __syncthreads();
    const unsigned cnt4 = cnt & ~3u;
    for (unsigned i = tid * 4; i < cnt4; i += 1024) {
        const uint4 r4 = *(const uint4*)&rec[i];
        atomicAdd(&table[r4.x >> 20], CNTONE | (unsigned long long)(r4.x & 0xFFFFFu));
        atomicAdd(&table[r4.y >> 20], CNTONE | (unsigned long long)(r4.y & 0xFFFFFu));
        atomicAdd(&table[r4.z >> 20], CNTONE | (unsigned long long)(r4.z & 0xFFFFFu));
        atomicAdd(&table[r4.w >> 20], CNTONE | (unsigned long long)(r4.w & 0xFFFFFu));
    }
    {
        const unsigned i = cnt4 + tid;
        if (i < cnt) {
            const unsigned r = rec[i];
            atomicAdd(&table[r >> 20],
                      CNTONE | (unsigned long long)(r & 0xFFFFFu));
        }
    }
    __syncthreads();
    const int node = (bkt << BSHIFT) + tid;
    if (node < N_NODESC) {
        const unsigned long long a = table[tid];
        const float sum = (float)(a & SUMMASK) * W20INV;
        const float cf = (float)(a >> 40);
        float2 r;
        r.x = rsqrtf(1.0f + sum);        // lp degree (self-loop = 1)
        r.y = rsqrtf(1.0f + cf - sum);   // hp degree
        (isD ? rD : rS)[node] = r;
    }
}

// ---------------------------------------------------------------------------
// final kernel: 512 threads, 4 CONSECUTIVE elements/thread, fully vectorized:
// int4 edge loads, float4 wlp load, float4 stores to both output ranges.
// Covers [0, MC): edge range + self-loop tail (boundary 16B-aligned).
__global__ __launch_bounds__(512) void final_kernel(
    const int* __restrict__ edges,
    const float2* __restrict__ rS,
    const float2* __restrict__ rD,
    float* __restrict__ out,
    const int* __restrict__ flag) {
    const int i0 = (blockIdx.x * 512 + threadIdx.x) * 4;
    if (i0 >= MC) return;
    if (i0 + 4 <= N_EDGESC) {
        const int is64 = *flag;
        int s[4], d[4];
        if (is64) {
            const int4 a0 = ((const int4*)edges)[i0 >> 1];
            const int4 a1 = ((const int4*)edges)[(i0 >> 1) + 1];
            const int4 b0 = ((const int4*)edges)[(N_EDGESC + i0) >> 1];
            const int4 b1 = ((const int4*)edges)[((N_EDGESC + i0) >> 1) + 1];
            s[0] = a0.x; s[1] = a0.z; s[2] = a1.x; s[3] = a1.z;
            d[0] = b0.x; d[1] = b0.z; d[2] = b1.x; d[3] = b1.z;
        } else {
            const int4 a = ((const int4*)edges)[i0 >> 2];
            const int4 b = ((const int4*)edges)[(N_EDGESC + i0) >> 2];
            s[0] = a.x; s[1] = a.y; s[2] = a.z; s[3] = a.w;
            d[0] = b.x; d[1] = b.y; d[2] = b.z; d[3] = b.w;
        }
        const float4 w4 = *(const float4*)&out[2 * MC + i0];
        float2 av[4], bv[4];
        #pragma unroll
        for (int j = 0; j < 4; ++j) { av[j] = rS[s[j]]; bv[j] = rD[d[j]]; }
        const float wl[4] = {w4.x + EOSC, w4.y + EOSC, w4.z + EOSC, w4.w + EOSC};
        const float wh[4] = {(1.0f - w4.x) + EOSC, (1.0f - w4.y) + EOSC,
                             (1.0f - w4.z) + EOSC, (1.0f - w4.w) + EOSC};
        float4 o1, o2;
        o1.x = wl[0] * av[0].x * bv[0].x;
        o1.y = wl[1] * av[1].x * bv[1].x;
        o1.z = wl[2] * av[2].x * bv[2].x;
        o1.w = wl[3] * av[3].x * bv[3].x;
        o2.x = -ALPHAC * wh[0] * av[0].y * bv[0].y;
        o2.y = -ALPHAC * wh[1] * av[1].y * bv[1].y;
        o2.z = -ALPHAC * wh[2] * av[2].y * bv[2].y;
        o2.w = -ALPHAC * wh[3] * av[3].y * bv[3].y;
        *(float4*)&out[i0] = o1;
        *(float4*)&out[MC + i0] = o2;
    } else {
        // self-loop tail: i0 >= N_EDGESC (boundary divisible by 4)
        const int n0 = i0 - N_EDGESC;
        float4 o1;
        float* o1p = (float*)&o1;
        #pragma unroll
        for (int j = 0; j < 4; ++j) {
            const int n = n0 + j;
            o1p[j] = 0.f;
            if (n < N_NODESC) {
                const float2 a = rS[n];
                const float2 b = rD[n];
                o1p[j] = (1.0f + EOSC) * a.x * b.x;
            }
        }
        if (n0 + 4 <= N_NODESC) {
            *(float4*)&out[i0] = o1;
            *(float4*)&out[MC + i0] = (float4){1.f, 1.f, 1.f, 1.f};
        } else {
            #pragma unroll
            for (int j = 0; j < 4; ++j) {
                if (n0 + j < N_NODESC) {
                    out[i0 + j] = o1p[j];
                    out[MC + i0 + j] = 1.0f;
                }
            }
        }
    }
}

// ---------------------------------------------------------------------------
extern "C" void kernel_launch(void* const* d_in, const int* in_sizes, int n_in,
                              void* d_out, int out_size, void* d_ws, size_t ws_size,
                              hipStream_t stream) {
    const float* features = (const float*)d_in[0];
    const int* edges      = (const int*)d_in[1];
    const float* noise    = (const float*)d_in[2];
    const float* W_emb    = (const float*)d_in[3];
    const float* b_emb    = (const float*)d_in[4];
    const float* W_edge   = (const float*)d_in[5];
    const float* b_edge   = (const float*)d_in[6];
    float* out = (float*)d_out;
    char* ws = (char*)d_ws;

    // ws layout (bytes):
    //   [0, 400000)            q  : N f32
    //   [400000, 1200000)      rS : N float2
    //   [1200000, 2000000)     rD : N float2
    //   [2000000, 2000004)     flag
    //   [2000064, 2003264)     cursor64 : 400 u64 (S low 32 | D high 32)
    //   [2097152, 10289152)    recS : 400*5120 u32
    //   [10289152, 18481152)   recD : 400*5120 u32
    float* q = (float*)ws;
    float2* rS = (float2*)(ws + 400000);
    float2* rD = (float2*)(ws + 1200000);
    int* flag = (int*)(ws + 2000000);
    unsigned long long* cursor64 = (unsigned long long*)(ws + 2000064);
    unsigned* recS = (unsigned*)(ws + 2097152);
    unsigned* recD = (unsigned*)(ws + 10289152);

    node_kernel<<<782, 256, 0, stream>>>(features, W_emb, b_emb, W_edge, edges,
                                         q, cursor64, flag);
    edge_scatter<<<(N_EDGESC / 4 + 511) / 512, 512, 0, stream>>>(
        edges, noise, b_edge, q, cursor64, recS, recD, out, flag);
    gather_kernel<<<2 * NBUCK_USED, 256, 0, stream>>>(recS, recD, cursor64, rS,
                                                      rD);
    final_kernel<<<(MC / 4 + 511) / 512, 512, 0, stream>>>(edges, rS, rD, out,
                                                           flag);
}